// Round 3
// baseline (232.221 us; speedup 1.0000x reference)
//
#include <hip/hip_runtime.h>
#include <stdint.h>

#define BB 8
#define NN 2048
#define DD 64
#define DELTA 0.1625f
#define FREQ_SCALE 0.325f

typedef __bf16 bf16x8 __attribute__((ext_vector_type(8)));
typedef float f32x4 __attribute__((ext_vector_type(4)));
typedef unsigned int u32x4 __attribute__((ext_vector_type(4)));
typedef unsigned int u32x2 __attribute__((ext_vector_type(2)));

static __device__ __forceinline__ unsigned short f2b(float x) {
    union { float f; unsigned int u; } c; c.f = x;
    unsigned int r = (c.u + 0x7FFFu + ((c.u >> 16) & 1u)) >> 16;
    return (unsigned short)r;
}

// ---------------- prep: normalize embeddings, echo layers, e0 (f32) + e0^T (bf16)
__global__ __launch_bounds__(256) void prep_norm(
        const float* __restrict__ emb, const float* __restrict__ freq,
        float* __restrict__ e0, unsigned short* __restrict__ eT0,
        int* __restrict__ echo) {
    __shared__ unsigned short tile[64][72];
    int t = threadIdx.x;
    int tok0 = blockIdx.x * 64;
    int lt = t >> 2;
    int tt = tok0 + lt;
    int dd = (t & 3) * 16;

    const float* src = emb + (size_t)tt * DD + dd;
    f32x4 v[4];
    float ss = 0.f;
    #pragma unroll
    for (int q = 0; q < 4; q++) {
        v[q] = *(const f32x4*)(src + q * 4);
        ss += v[q].x*v[q].x + v[q].y*v[q].y + v[q].z*v[q].z + v[q].w*v[q].w;
    }
    ss += __shfl_xor(ss, 1);
    ss += __shfl_xor(ss, 2);
    float scale = 1.f / fmaxf(sqrtf(ss), 1e-12f);
    float* dst = e0 + (size_t)tt * DD + dd;
    #pragma unroll
    for (int q = 0; q < 4; q++) {
        f32x4 o = v[q] * scale;
        *(f32x4*)(dst + q * 4) = o;
        tile[lt][dd + q*4 + 0] = f2b(o.x);
        tile[lt][dd + q*4 + 1] = f2b(o.y);
        tile[lt][dd + q*4 + 2] = f2b(o.z);
        tile[lt][dd + q*4 + 3] = f2b(o.w);
    }
    if ((t & 3) == 0) {
        int el = 1 + (int)floorf(freq[tt] * FREQ_SCALE);
        el = el < 1 ? 1 : (el > 5 ? 5 : el);
        echo[tt] = el;
    }
    __syncthreads();
    int b  = tok0 / NN;
    int tb = tok0 % NN;
    for (int idx = t; idx < 64 * 64; idx += 256) {
        int d = idx >> 6, j = idx & 63;
        eT0[((size_t)b * DD + d) * NN + tb + j] = tile[j][d];
    }
}

// ---------------- cast + rowsum: one wave per rm row, pure streaming
template<bool WRB>
__global__ __launch_bounds__(256) void cast_rowsum(
        const float* __restrict__ rm, unsigned short* __restrict__ rmb,
        float* __restrict__ rowsum) {
    int gw = (int)((blockIdx.x * 256 + threadIdx.x) >> 6);   // row 0..B*N-1
    int l = threadIdx.x & 63;
    const float* src = rm + (size_t)gw * NN;
    f32x4 v[8];
    #pragma unroll
    for (int q = 0; q < 8; q++)
        v[q] = *(const f32x4*)(src + q * 256 + l * 4);
    float s = 0.f;
    #pragma unroll
    for (int q = 0; q < 8; q++)
        s += (v[q].x + v[q].y) + (v[q].z + v[q].w);
    if constexpr (WRB) {
        unsigned short* dst = rmb + (size_t)gw * NN;
        #pragma unroll
        for (int q = 0; q < 8; q++) {
            u32x2 o;
            o.x = (unsigned)f2b(v[q].x) | ((unsigned)f2b(v[q].y) << 16);
            o.y = (unsigned)f2b(v[q].z) | ((unsigned)f2b(v[q].w) << 16);
            *(u32x2*)(dst + q * 256 + l * 4) = o;
        }
    }
    #pragma unroll
    for (int m = 1; m < 64; m <<= 1) s += __shfl_xor(s, m);
    if (l == 0) rowsum[gw] = s;
}

// ---------------- layer step: agg^T = e^T * rm^T via MFMA, fused epilogue
// 512 threads = 8 waves: wi = w&1 (16-row i-tile), kq = w>>1 (K quarter of 512).
// No global stores inside the K loop; dual-stream double-buffered prefetch.
template<bool RD32>
__global__ __launch_bounds__(512, 4) void layer_step(
        const void* __restrict__ rm_,
        const unsigned short* __restrict__ eT_src,  // [B][64][N] bf16
        const float* __restrict__ e_src,            // [B][N][64] f32
        const float* __restrict__ rowsum_g,
        const int* __restrict__ echo,
        float* __restrict__ e_dst,
        unsigned short* __restrict__ eT_dst,
        int layer) {
    __shared__ float redAcc[3][2][64][20];   // pad 16->20 to break bank conflicts

    int t = threadIdx.x;
    int w = t >> 6, l = t & 63;
    int b = blockIdx.y;
    int i0 = blockIdx.x * 32;
    int wi = w & 1;
    int kq = w >> 1;
    int lane_lo = l & 15, lane_hi = l >> 4;
    int i = i0 + wi * 16 + lane_lo;
    size_t gi = (size_t)b * NN + i;
    int kbase = kq * (NN / 4) + 8 * lane_hi;

    int echo_pre = echo[gi];
    float rs = rowsum_g[gi];

    const unsigned short* eT_b = eT_src + (size_t)b * DD * NN;
    const unsigned short* ea0 = eT_b + (size_t)(lane_lo)      * NN + kbase;
    const unsigned short* ea1 = eT_b + (size_t)(16 + lane_lo) * NN + kbase;
    const unsigned short* ea2 = eT_b + (size_t)(32 + lane_lo) * NN + kbase;
    const unsigned short* ea3 = eT_b + (size_t)(48 + lane_lo) * NN + kbase;

    f32x4 acc[4] = {};

    u32x4 av[2][4];
    u32x4 rv[2];
    f32x4 rA[2], rB[2];
    size_t rm_row = gi * NN;

    const unsigned short* rmp16 = (const unsigned short*)rm_ + rm_row + kbase;
    const float* rmp32 = (const float*)rm_ + rm_row + kbase;

    // prologue: load j=0
    if constexpr (RD32) { rA[0] = *(const f32x4*)(rmp32); rB[0] = *(const f32x4*)(rmp32 + 4); }
    else                { rv[0] = *(const u32x4*)(rmp16); }
    av[0][0] = *(const u32x4*)(ea0);
    av[0][1] = *(const u32x4*)(ea1);
    av[0][2] = *(const u32x4*)(ea2);
    av[0][3] = *(const u32x4*)(ea3);

    #pragma unroll
    for (int j = 0; j < 16; j++) {
        const int cur = j & 1, nxt = cur ^ 1;
        if (j < 15) {
            const int o = 32 * (j + 1);
            if constexpr (RD32) {
                rA[nxt] = *(const f32x4*)(rmp32 + o);
                rB[nxt] = *(const f32x4*)(rmp32 + o + 4);
            } else {
                rv[nxt] = *(const u32x4*)(rmp16 + o);
            }
            av[nxt][0] = *(const u32x4*)(ea0 + o);
            av[nxt][1] = *(const u32x4*)(ea1 + o);
            av[nxt][2] = *(const u32x4*)(ea2 + o);
            av[nxt][3] = *(const u32x4*)(ea3 + o);
        }
        bf16x8 bfrag;
        if constexpr (RD32) {
            f32x4 lo = rA[cur], hi = rB[cur];
            u32x4 o;
            o.x = (unsigned)f2b(lo.x) | ((unsigned)f2b(lo.y) << 16);
            o.y = (unsigned)f2b(lo.z) | ((unsigned)f2b(lo.w) << 16);
            o.z = (unsigned)f2b(hi.x) | ((unsigned)f2b(hi.y) << 16);
            o.w = (unsigned)f2b(hi.z) | ((unsigned)f2b(hi.w) << 16);
            bfrag = __builtin_bit_cast(bf16x8, o);
        } else {
            bfrag = __builtin_bit_cast(bf16x8, rv[cur]);
        }
        acc[0] = __builtin_amdgcn_mfma_f32_16x16x32_bf16(
            __builtin_bit_cast(bf16x8, av[cur][0]), bfrag, acc[0], 0, 0, 0);
        acc[1] = __builtin_amdgcn_mfma_f32_16x16x32_bf16(
            __builtin_bit_cast(bf16x8, av[cur][1]), bfrag, acc[1], 0, 0, 0);
        acc[2] = __builtin_amdgcn_mfma_f32_16x16x32_bf16(
            __builtin_bit_cast(bf16x8, av[cur][2]), bfrag, acc[2], 0, 0, 0);
        acc[3] = __builtin_amdgcn_mfma_f32_16x16x32_bf16(
            __builtin_bit_cast(bf16x8, av[cur][3]), bfrag, acc[3], 0, 0, 0);
    }

    if (kq > 0) {
        #pragma unroll
        for (int f = 0; f < 4; f++)
            *(f32x4*)(&redAcc[kq - 1][wi][l][4 * f]) = acc[f];
    }
    __syncthreads();
    if (kq == 0) {
        #pragma unroll
        for (int f = 0; f < 4; f++) {
            acc[f] += *(const f32x4*)(&redAcc[0][wi][l][4 * f]);
            acc[f] += *(const f32x4*)(&redAcc[1][wi][l][4 * f]);
            acc[f] += *(const f32x4*)(&redAcc[2][wi][l][4 * f]);
        }
        float active = (layer < echo_pre) ? 1.f : 0.f;
        float coef = DELTA * active;
        size_t ebase = gi * DD;
        f32x4 upd[4];
        float ss = 0.f;
        #pragma unroll
        for (int f = 0; f < 4; f++) {
            f32x4 e = *(const f32x4*)(e_src + ebase + 16 * f + 4 * lane_hi);
            f32x4 u = e + coef * (e * rs - acc[f]);
            upd[f] = u;
            ss += u.x*u.x + u.y*u.y + u.z*u.z + u.w*u.w;
        }
        ss += __shfl_xor(ss, 16);
        ss += __shfl_xor(ss, 32);
        float scale = 1.f / fmaxf(sqrtf(ss), 1e-12f);
        unsigned short* ep = eT_dst + (size_t)b * DD * NN;
        #pragma unroll
        for (int f = 0; f < 4; f++) {
            f32x4 o = upd[f] * scale;
            *(f32x4*)(e_dst + ebase + 16 * f + 4 * lane_hi) = o;
            int dbase = 16 * f + 4 * lane_hi;
            ep[(size_t)(dbase + 0) * NN + i] = f2b(o.x);
            ep[(size_t)(dbase + 1) * NN + i] = f2b(o.y);
            ep[(size_t)(dbase + 2) * NN + i] = f2b(o.z);
            ep[(size_t)(dbase + 3) * NN + i] = f2b(o.w);
        }
    }
}

extern "C" void kernel_launch(void* const* d_in, const int* in_sizes, int n_in,
                              void* d_out, int out_size, void* d_ws, size_t ws_size,
                              hipStream_t stream) {
    const float* emb  = (const float*)d_in[0];
    const float* freq = (const float*)d_in[1];
    const float* rm   = (const float*)d_in[2];
    float* out = (float*)d_out;
    char* ws = (char*)d_ws;

    const size_t eBytes   = (size_t)BB * NN * DD * 4;   // 4 MB
    const size_t eTBytes  = (size_t)BB * DD * NN * 2;   // 2 MB
    const size_t bnBytes  = (size_t)BB * NN * 4;        // 64 KB
    const size_t rmbBytes = (size_t)BB * NN * NN * 2;   // 67 MB
    float* e_f32[2] = { (float*)ws, (float*)(ws + eBytes) };
    unsigned short* eT[2] = { (unsigned short*)(ws + 2*eBytes),
                              (unsigned short*)(ws + 2*eBytes + eTBytes) };
    float* rowsum = (float*)(ws + 2*eBytes + 2*eTBytes);
    int* echo = (int*)(ws + 2*eBytes + 2*eTBytes + bnBytes);
    unsigned short* rmb = (unsigned short*)(ws + 2*eBytes + 2*eTBytes + 2*bnBytes);
    size_t need_cached = 2*eBytes + 2*eTBytes + 2*bnBytes + rmbBytes;
    int cached = (ws_size >= need_cached) ? 1 : 0;

    prep_norm<<<dim3(BB*NN/64), dim3(256), 0, stream>>>(emb, freq, e_f32[0], eT[0], echo);

    dim3 lgrid(NN/32, BB), lblk(512);
    if (cached) {
        cast_rowsum<true><<<dim3(BB*NN/4), dim3(256), 0, stream>>>(rm, rmb, rowsum);
        for (int l = 0; l < 5; l++) {
            float* dst = (l == 4) ? out : e_f32[(l + 1) & 1];
            layer_step<false><<<lgrid, lblk, 0, stream>>>(
                (const void*)rmb, eT[l & 1], e_f32[l & 1], rowsum, echo,
                dst, eT[(l + 1) & 1], l);
        }
    } else {
        cast_rowsum<false><<<dim3(BB*NN/4), dim3(256), 0, stream>>>(rm, nullptr, rowsum);
        for (int l = 0; l < 5; l++) {
            float* dst = (l == 4) ? out : e_f32[(l + 1) & 1];
            layer_step<true><<<lgrid, lblk, 0, stream>>>(
                (const void*)rm, eT[l & 1], e_f32[l & 1], rowsum, echo,
                dst, eT[(l + 1) & 1], l);
        }
    }
}

// Round 6
// 152.071 us; speedup vs baseline: 1.5271x; 1.5271x over previous
//
#include <hip/hip_runtime.h>
#include <stdint.h>

#define BB 8
#define NN 2048
#define DD 64
#define DELTA 0.1625f
#define FREQ_SCALE 0.325f

typedef __bf16 bf16x8 __attribute__((ext_vector_type(8)));
typedef float f32x4 __attribute__((ext_vector_type(4)));
typedef unsigned int u32x4 __attribute__((ext_vector_type(4)));
typedef unsigned int u32x2 __attribute__((ext_vector_type(2)));

static __device__ __forceinline__ unsigned short f2b(float x) {
    union { float f; unsigned int u; } c; c.f = x;
    unsigned int r = (c.u + 0x7FFFu + ((c.u >> 16) & 1u)) >> 16;
    return (unsigned short)r;
}

static __device__ __forceinline__ void gl_lds16(const void* g, void* l) {
    __builtin_amdgcn_global_load_lds(
        (const __attribute__((address_space(1))) void*)g,
        (__attribute__((address_space(3))) void*)l, 16, 0, 0);
}

// ---------------- prep: normalize embeddings, echo layers, e0 (f32) + e0^T (bf16)
__global__ __launch_bounds__(256) void prep_norm(
        const float* __restrict__ emb, const float* __restrict__ freq,
        float* __restrict__ e0, unsigned short* __restrict__ eT0,
        int* __restrict__ echo) {
    __shared__ unsigned short tile[64][72];
    int t = threadIdx.x;
    int tok0 = blockIdx.x * 64;
    int lt = t >> 2;
    int tt = tok0 + lt;
    int dd = (t & 3) * 16;

    const float* src = emb + (size_t)tt * DD + dd;
    f32x4 v[4];
    float ss = 0.f;
    #pragma unroll
    for (int q = 0; q < 4; q++) {
        v[q] = *(const f32x4*)(src + q * 4);
        ss += v[q].x*v[q].x + v[q].y*v[q].y + v[q].z*v[q].z + v[q].w*v[q].w;
    }
    ss += __shfl_xor(ss, 1);
    ss += __shfl_xor(ss, 2);
    float scale = 1.f / fmaxf(sqrtf(ss), 1e-12f);
    float* dst = e0 + (size_t)tt * DD + dd;
    #pragma unroll
    for (int q = 0; q < 4; q++) {
        f32x4 o = v[q] * scale;
        *(f32x4*)(dst + q * 4) = o;
        tile[lt][dd + q*4 + 0] = f2b(o.x);
        tile[lt][dd + q*4 + 1] = f2b(o.y);
        tile[lt][dd + q*4 + 2] = f2b(o.z);
        tile[lt][dd + q*4 + 3] = f2b(o.w);
    }
    if ((t & 3) == 0) {
        int el = 1 + (int)floorf(freq[tt] * FREQ_SCALE);
        el = el < 1 ? 1 : (el > 5 ? 5 : el);
        echo[tt] = el;
    }
    __syncthreads();
    int b  = tok0 / NN;
    int tb = tok0 % NN;
    for (int idx = t; idx < 64 * 64; idx += 256) {
        int d = idx >> 6, j = idx & 63;
        eT0[((size_t)b * DD + d) * NN + tb + j] = tile[j][d];
    }
}

// ---------------- cast + rowsum: one wave per rm row, pure streaming
template<bool WRB>
__global__ __launch_bounds__(256) void cast_rowsum(
        const float* __restrict__ rm, unsigned short* __restrict__ rmb,
        float* __restrict__ rowsum) {
    int gw = (int)((blockIdx.x * 256 + threadIdx.x) >> 6);   // row 0..B*N-1
    int l = threadIdx.x & 63;
    const float* src = rm + (size_t)gw * NN;
    f32x4 v[8];
    #pragma unroll
    for (int q = 0; q < 8; q++)
        v[q] = *(const f32x4*)(src + q * 256 + l * 4);
    float s = 0.f;
    #pragma unroll
    for (int q = 0; q < 8; q++)
        s += (v[q].x + v[q].y) + (v[q].z + v[q].w);
    if constexpr (WRB) {
        unsigned short* dst = rmb + (size_t)gw * NN;
        #pragma unroll
        for (int q = 0; q < 8; q++) {
            u32x2 o;
            o.x = (unsigned)f2b(v[q].x) | ((unsigned)f2b(v[q].y) << 16);
            o.y = (unsigned)f2b(v[q].z) | ((unsigned)f2b(v[q].w) << 16);
            *(u32x2*)(dst + q * 256 + l * 4) = o;
        }
    }
    #pragma unroll
    for (int m = 1; m < 64; m <<= 1) s += __shfl_xor(s, m);
    if (l == 0) rowsum[gw] = s;
}

// ---------------- layer step (LDS-staged MFMA, m97 pattern)
// grid (NN/32, BB), block 256 = 4 waves: wi = w>>1 (16-row i-tile), dh = w&1 (32-col d-half).
// Tiles (bf16, XOR-swizzled byte ^= ((row&7)<<4) within 256B row):
//   SB = rm[32 i][128 k], SA = eT[64 d][128 k]; double-buffered; K loop 16 steps.
__global__ __launch_bounds__(256, 2) void layer_mfma(
        const unsigned short* __restrict__ rmb,     // [B][N][N] bf16
        const unsigned short* __restrict__ eT_src,  // [B][64][N] bf16
        const float* __restrict__ e_src,            // [B][N][64] f32
        const float* __restrict__ rowsum_g,
        const int* __restrict__ echo,
        float* __restrict__ e_dst,
        unsigned short* __restrict__ eT_dst,
        int layer) {
    __shared__ u32x4 SA[2][64 * 16];   // 32 KB
    __shared__ u32x4 SB[2][32 * 16];   // 16 KB
    __shared__ float redSS[2][2][16];

    const int t = threadIdx.x;
    const int w = t >> 6, l = t & 63;
    const int lo = l & 15, hi = l >> 4;
    const int wi = w >> 1, dh = w & 1;
    const int b = blockIdx.y;
    const int i0 = blockIdx.x * 32;

    // staging lane decomposition: 4 rows x 256B per instruction
    const int sr  = l >> 4;            // row within 4-row group
    const int scb = (l & 15) << 4;     // byte col within 256B row

    const char* rm_bytes = (const char*)(rmb + ((size_t)b * NN + i0) * NN);
    const char* eT_bytes = (const char*)(eT_src + (size_t)b * DD * NN);

    f32x4 acc0 = {}, acc1 = {};

    // per-lane swizzled column offsets for staging (row-dependent XOR)
    // rm rows handled by this wave: w*8 + {0..7}; eT rows: w*16 + {0..15}
    #define STAGE(buf, step) do {                                              \
        const int ksb = (step) * 256;                                          \
        {   int r0 = w * 8;                                                    \
            int lr = r0 + sr;                                                  \
            gl_lds16(rm_bytes + (size_t)lr * (NN*2) + ksb + (scb ^ ((lr&7)<<4)),\
                     (char*)&SB[buf][0] + r0 * 256);                           \
            r0 += 4; lr = r0 + sr;                                             \
            gl_lds16(rm_bytes + (size_t)lr * (NN*2) + ksb + (scb ^ ((lr&7)<<4)),\
                     (char*)&SB[buf][0] + r0 * 256); }                         \
        _Pragma("unroll")                                                      \
        for (int q = 0; q < 4; q++) {                                          \
            int r0 = w * 16 + q * 4;                                           \
            int lr = r0 + sr;                                                  \
            gl_lds16(eT_bytes + (size_t)lr * (NN*2) + ksb + (scb ^ ((lr&7)<<4)),\
                     (char*)&SA[buf][0] + r0 * 256); }                         \
    } while (0)

    const int rowB = wi * 16 + lo;          // rm row (i)
    const int rowA0 = dh * 32 + lo;         // eT row, dt=0
    const int rowA1 = dh * 32 + 16 + lo;    // eT row, dt=1
    const int xr = (lo & 7) << 4;           // XOR key: rows ≡ lo (mod 8) for all three streams

    #define COMPUTE(buf) do {                                                  \
        const char* Ab = (const char*)&SA[buf][0];                             \
        const char* Bb = (const char*)&SB[buf][0];                             \
        _Pragma("unroll")                                                      \
        for (int kk = 0; kk < 4; kk++) {                                       \
            int co = ((kk << 6) | (hi << 4)) ^ xr;                             \
            u32x4 fB  = *(const u32x4*)(Bb + rowB  * 256 + co);                \
            u32x4 fA0 = *(const u32x4*)(Ab + rowA0 * 256 + co);                \
            u32x4 fA1 = *(const u32x4*)(Ab + rowA1 * 256 + co);                \
            acc0 = __builtin_amdgcn_mfma_f32_16x16x32_bf16(                    \
                __builtin_bit_cast(bf16x8, fA0), __builtin_bit_cast(bf16x8, fB), acc0, 0, 0, 0); \
            acc1 = __builtin_amdgcn_mfma_f32_16x16x32_bf16(                    \
                __builtin_bit_cast(bf16x8, fA1), __builtin_bit_cast(bf16x8, fB), acc1, 0, 0, 0); \
        }                                                                      \
    } while (0)

    STAGE(0, 0);
    __syncthreads();
    #pragma unroll
    for (int step = 0; step < 16; step++) {
        const int cur = step & 1;
        if (step < 15) STAGE(cur ^ 1, step + 1);
        COMPUTE(cur);
        __syncthreads();
    }
    #undef STAGE
    #undef COMPUTE

    // epilogue: i = i0 + wi*16 + lo ; d = dh*32 + dt*16 + hi*4 + r
    const size_t gi = (size_t)b * NN + i0 + wi * 16 + lo;
    const float rs = rowsum_g[gi];
    const float coef = (layer < echo[gi]) ? DELTA : 0.f;
    const size_t eb = gi * DD + dh * 32 + hi * 4;
    f32x4 e0 = *(const f32x4*)(e_src + eb);
    f32x4 e1 = *(const f32x4*)(e_src + eb + 16);
    f32x4 u0 = e0 + coef * (e0 * rs - acc0);
    f32x4 u1 = e1 + coef * (e1 * rs - acc1);
    float ss = u0.x*u0.x + u0.y*u0.y + u0.z*u0.z + u0.w*u0.w
             + u1.x*u1.x + u1.y*u1.y + u1.z*u1.z + u1.w*u1.w;
    ss += __shfl_xor(ss, 16);
    ss += __shfl_xor(ss, 32);
    if (hi == 0) redSS[wi][dh][lo] = ss;
    __syncthreads();
    float sst = redSS[wi][0][lo] + redSS[wi][1][lo];
    float scale = 1.f / fmaxf(sqrtf(sst), 1e-12f);
    u0 *= scale;
    u1 *= scale;
    *(f32x4*)(e_dst + eb) = u0;
    *(f32x4*)(e_dst + eb + 16) = u1;
    unsigned short* ep = eT_dst + (size_t)b * DD * NN;
    const int i = i0 + wi * 16 + lo;
    const int d0 = dh * 32 + hi * 4;
    ep[(size_t)(d0 + 0)  * NN + i] = f2b(u0.x);
    ep[(size_t)(d0 + 1)  * NN + i] = f2b(u0.y);
    ep[(size_t)(d0 + 2)  * NN + i] = f2b(u0.z);
    ep[(size_t)(d0 + 3)  * NN + i] = f2b(u0.w);
    ep[(size_t)(d0 + 16) * NN + i] = f2b(u1.x);
    ep[(size_t)(d0 + 17) * NN + i] = f2b(u1.y);
    ep[(size_t)(d0 + 18) * NN + i] = f2b(u1.z);
    ep[(size_t)(d0 + 19) * NN + i] = f2b(u1.w);
}

// ---------------- fallback (no bf16 cache fits): direct fp32 reads, R3 structure
__global__ __launch_bounds__(512, 4) void layer_step_fb(
        const float* __restrict__ rm_,
        const unsigned short* __restrict__ eT_src,
        const float* __restrict__ e_src,
        const float* __restrict__ rowsum_g,
        const int* __restrict__ echo,
        float* __restrict__ e_dst,
        unsigned short* __restrict__ eT_dst,
        int layer) {
    __shared__ float redAcc[3][2][64][20];

    int t = threadIdx.x;
    int w = t >> 6, l = t & 63;
    int b = blockIdx.y;
    int i0 = blockIdx.x * 32;
    int wi = w & 1;
    int kq = w >> 1;
    int lane_lo = l & 15, lane_hi = l >> 4;
    int i = i0 + wi * 16 + lane_lo;
    size_t gi = (size_t)b * NN + i;
    int kbase = kq * (NN / 4) + 8 * lane_hi;

    int echo_pre = echo[gi];
    float rs = rowsum_g[gi];

    const unsigned short* eT_b = eT_src + (size_t)b * DD * NN;
    const unsigned short* ea0 = eT_b + (size_t)(lane_lo)      * NN + kbase;
    const unsigned short* ea1 = eT_b + (size_t)(16 + lane_lo) * NN + kbase;
    const unsigned short* ea2 = eT_b + (size_t)(32 + lane_lo) * NN + kbase;
    const unsigned short* ea3 = eT_b + (size_t)(48 + lane_lo) * NN + kbase;

    f32x4 acc[4] = {};
    const float* rmp32 = rm_ + gi * NN + kbase;

    #pragma unroll
    for (int j = 0; j < 16; j++) {
        const int o = 32 * j;
        f32x4 lo4 = *(const f32x4*)(rmp32 + o);
        f32x4 hi4 = *(const f32x4*)(rmp32 + o + 4);
        u32x4 ob;
        ob.x = (unsigned)f2b(lo4.x) | ((unsigned)f2b(lo4.y) << 16);
        ob.y = (unsigned)f2b(lo4.z) | ((unsigned)f2b(lo4.w) << 16);
        ob.z = (unsigned)f2b(hi4.x) | ((unsigned)f2b(hi4.y) << 16);
        ob.w = (unsigned)f2b(hi4.z) | ((unsigned)f2b(hi4.w) << 16);
        bf16x8 bfrag = __builtin_bit_cast(bf16x8, ob);
        acc[0] = __builtin_amdgcn_mfma_f32_16x16x32_bf16(
            __builtin_bit_cast(bf16x8, *(const u32x4*)(ea0 + o)), bfrag, acc[0], 0, 0, 0);
        acc[1] = __builtin_amdgcn_mfma_f32_16x16x32_bf16(
            __builtin_bit_cast(bf16x8, *(const u32x4*)(ea1 + o)), bfrag, acc[1], 0, 0, 0);
        acc[2] = __builtin_amdgcn_mfma_f32_16x16x32_bf16(
            __builtin_bit_cast(bf16x8, *(const u32x4*)(ea2 + o)), bfrag, acc[2], 0, 0, 0);
        acc[3] = __builtin_amdgcn_mfma_f32_16x16x32_bf16(
            __builtin_bit_cast(bf16x8, *(const u32x4*)(ea3 + o)), bfrag, acc[3], 0, 0, 0);
    }

    if (kq > 0) {
        #pragma unroll
        for (int f = 0; f < 4; f++)
            *(f32x4*)(&redAcc[kq - 1][wi][l][4 * f]) = acc[f];
    }
    __syncthreads();
    if (kq == 0) {
        #pragma unroll
        for (int f = 0; f < 4; f++) {
            acc[f] += *(const f32x4*)(&redAcc[0][wi][l][4 * f]);
            acc[f] += *(const f32x4*)(&redAcc[1][wi][l][4 * f]);
            acc[f] += *(const f32x4*)(&redAcc[2][wi][l][4 * f]);
        }
        float coef = DELTA * ((layer < echo_pre) ? 1.f : 0.f);
        size_t ebase = gi * DD;
        f32x4 upd[4];
        float ss = 0.f;
        #pragma unroll
        for (int f = 0; f < 4; f++) {
            f32x4 e = *(const f32x4*)(e_src + ebase + 16 * f + 4 * lane_hi);
            f32x4 u = e + coef * (e * rs - acc[f]);
            upd[f] = u;
            ss += u.x*u.x + u.y*u.y + u.z*u.z + u.w*u.w;
        }
        ss += __shfl_xor(ss, 16);
        ss += __shfl_xor(ss, 32);
        float scale = 1.f / fmaxf(sqrtf(ss), 1e-12f);
        unsigned short* ep = eT_dst + (size_t)b * DD * NN;
        #pragma unroll
        for (int f = 0; f < 4; f++) {
            f32x4 o = upd[f] * scale;
            *(f32x4*)(e_dst + ebase + 16 * f + 4 * lane_hi) = o;
            int dbase = 16 * f + 4 * lane_hi;
            ep[(size_t)(dbase + 0) * NN + i] = f2b(o.x);
            ep[(size_t)(dbase + 1) * NN + i] = f2b(o.y);
            ep[(size_t)(dbase + 2) * NN + i] = f2b(o.z);
            ep[(size_t)(dbase + 3) * NN + i] = f2b(o.w);
        }
    }
}

extern "C" void kernel_launch(void* const* d_in, const int* in_sizes, int n_in,
                              void* d_out, int out_size, void* d_ws, size_t ws_size,
                              hipStream_t stream) {
    const float* emb  = (const float*)d_in[0];
    const float* freq = (const float*)d_in[1];
    const float* rm   = (const float*)d_in[2];
    float* out = (float*)d_out;
    char* ws = (char*)d_ws;

    const size_t eBytes   = (size_t)BB * NN * DD * 4;   // 4 MB
    const size_t eTBytes  = (size_t)BB * DD * NN * 2;   // 2 MB
    const size_t bnBytes  = (size_t)BB * NN * 4;        // 64 KB
    const size_t rmbBytes = (size_t)BB * NN * NN * 2;   // 67 MB
    float* e_f32[2] = { (float*)ws, (float*)(ws + eBytes) };
    unsigned short* eT[2] = { (unsigned short*)(ws + 2*eBytes),
                              (unsigned short*)(ws + 2*eBytes + eTBytes) };
    float* rowsum = (float*)(ws + 2*eBytes + 2*eTBytes);
    int* echo = (int*)(ws + 2*eBytes + 2*eTBytes + bnBytes);
    unsigned short* rmb = (unsigned short*)(ws + 2*eBytes + 2*eTBytes + 2*bnBytes);
    size_t need_cached = 2*eBytes + 2*eTBytes + 2*bnBytes + rmbBytes;
    int cached = (ws_size >= need_cached) ? 1 : 0;

    prep_norm<<<dim3(BB*NN/64), dim3(256), 0, stream>>>(emb, freq, e_f32[0], eT[0], echo);

    if (cached) {
        cast_rowsum<true><<<dim3(BB*NN/4), dim3(256), 0, stream>>>(rm, rmb, rowsum);
        for (int l = 0; l < 5; l++) {
            float* dst = (l == 4) ? out : e_f32[(l + 1) & 1];
            layer_mfma<<<dim3(NN/32, BB), dim3(256), 0, stream>>>(
                rmb, eT[l & 1], e_f32[l & 1], rowsum, echo,
                dst, eT[(l + 1) & 1], l);
        }
    } else {
        cast_rowsum<false><<<dim3(BB*NN/4), dim3(256), 0, stream>>>(rm, nullptr, rowsum);
        for (int l = 0; l < 5; l++) {
            float* dst = (l == 4) ? out : e_f32[(l + 1) & 1];
            layer_step_fb<<<dim3(NN/32, BB), dim3(512), 0, stream>>>(
                rm, eT[l & 1], e_f32[l & 1], rowsum, echo,
                dst, eT[(l + 1) & 1], l);
        }
    }
}

// Round 8
// 143.090 us; speedup vs baseline: 1.6229x; 1.0628x over previous
//
#include <hip/hip_runtime.h>
#include <stdint.h>

#define BB 8
#define NN 2048
#define DD 64
#define DELTA 0.1625f
#define FREQ_SCALE 0.325f

typedef __bf16 bf16x8 __attribute__((ext_vector_type(8)));
typedef float f32x4 __attribute__((ext_vector_type(4)));
typedef unsigned int u32x4 __attribute__((ext_vector_type(4)));
typedef unsigned int u32x2 __attribute__((ext_vector_type(2)));

static __device__ __forceinline__ unsigned short f2b(float x) {
    union { float f; unsigned int u; } c; c.f = x;
    unsigned int r = (c.u + 0x7FFFu + ((c.u >> 16) & 1u)) >> 16;
    return (unsigned short)r;
}

static __device__ __forceinline__ void gl_lds16(const void* g, void* l) {
    __builtin_amdgcn_global_load_lds(
        (const __attribute__((address_space(1))) void*)g,
        (__attribute__((address_space(3))) void*)l, 16, 0, 0);
}

// ---------------- prep: normalize embeddings, echo layers, e0 (f32) + e0^T (bf16)
__global__ __launch_bounds__(256) void prep_norm(
        const float* __restrict__ emb, const float* __restrict__ freq,
        float* __restrict__ e0, unsigned short* __restrict__ eT0,
        int* __restrict__ echo) {
    __shared__ unsigned short tile[64][72];
    int t = threadIdx.x;
    int tok0 = blockIdx.x * 64;
    int lt = t >> 2;
    int tt = tok0 + lt;
    int dd = (t & 3) * 16;

    const float* src = emb + (size_t)tt * DD + dd;
    f32x4 v[4];
    float ss = 0.f;
    #pragma unroll
    for (int q = 0; q < 4; q++) {
        v[q] = *(const f32x4*)(src + q * 4);
        ss += v[q].x*v[q].x + v[q].y*v[q].y + v[q].z*v[q].z + v[q].w*v[q].w;
    }
    ss += __shfl_xor(ss, 1);
    ss += __shfl_xor(ss, 2);
    float scale = 1.f / fmaxf(sqrtf(ss), 1e-12f);
    float* dst = e0 + (size_t)tt * DD + dd;
    #pragma unroll
    for (int q = 0; q < 4; q++) {
        f32x4 o = v[q] * scale;
        *(f32x4*)(dst + q * 4) = o;
        tile[lt][dd + q*4 + 0] = f2b(o.x);
        tile[lt][dd + q*4 + 1] = f2b(o.y);
        tile[lt][dd + q*4 + 2] = f2b(o.z);
        tile[lt][dd + q*4 + 3] = f2b(o.w);
    }
    if ((t & 3) == 0) {
        int el = 1 + (int)floorf(freq[tt] * FREQ_SCALE);
        el = el < 1 ? 1 : (el > 5 ? 5 : el);
        echo[tt] = el;
    }
    __syncthreads();
    int b  = tok0 / NN;
    int tb = tok0 % NN;
    for (int idx = t; idx < 64 * 64; idx += 256) {
        int d = idx >> 6, j = idx & 63;
        eT0[((size_t)b * DD + d) * NN + tb + j] = tile[j][d];
    }
}

// ---------------- cast + rowsum: one wave per rm row, pure streaming
template<bool WRB>
__global__ __launch_bounds__(256) void cast_rowsum(
        const float* __restrict__ rm, unsigned short* __restrict__ rmb,
        float* __restrict__ rowsum) {
    int gw = (int)((blockIdx.x * 256 + threadIdx.x) >> 6);   // row 0..B*N-1
    int l = threadIdx.x & 63;
    const float* src = rm + (size_t)gw * NN;
    f32x4 v[8];
    #pragma unroll
    for (int q = 0; q < 8; q++)
        v[q] = *(const f32x4*)(src + q * 256 + l * 4);
    float s = 0.f;
    #pragma unroll
    for (int q = 0; q < 8; q++)
        s += (v[q].x + v[q].y) + (v[q].z + v[q].w);
    if constexpr (WRB) {
        unsigned short* dst = rmb + (size_t)gw * NN;
        #pragma unroll
        for (int q = 0; q < 8; q++) {
            u32x2 o;
            o.x = (unsigned)f2b(v[q].x) | ((unsigned)f2b(v[q].y) << 16);
            o.y = (unsigned)f2b(v[q].z) | ((unsigned)f2b(v[q].w) << 16);
            *(u32x2*)(dst + q * 256 + l * 4) = o;
        }
    }
    #pragma unroll
    for (int m = 1; m < 64; m <<= 1) s += __shfl_xor(s, m);
    if (l == 0) rowsum[gw] = s;
}

// ---------------- layer K-split kernel: partial agg^T over half the K range
// grid (NN/64, 2, BB), block 512 = 8 waves: it = w&3 (16-row i-tile), dh = w>>2.
// SB = rm[64 i][128 k], SA = eT[64 d][128 k]; double-buffered; 8 K-steps of 128.
__global__ __launch_bounds__(512, 2) void layer_ksplit(
        const unsigned short* __restrict__ rmb,     // [B][N][N] bf16
        const unsigned short* __restrict__ eT_src,  // [B][64][N] bf16
        float* __restrict__ partial) {              // [2][B][N][64] f32
    __shared__ u32x4 SA[2][64 * 16];   // 16 KB each buf
    __shared__ u32x4 SB[2][64 * 16];

    const int t = threadIdx.x;
    const int w = t >> 6, l = t & 63;
    const int lo = l & 15, hi = l >> 4;
    const int it = w & 3, dh = w >> 2;
    const int i0 = blockIdx.x * 64;
    const int ks = blockIdx.y;
    const int b  = blockIdx.z;
    const int kb0 = ks * (NN / 2);

    const int sr  = l >> 4;            // staging row within 4-row group
    const int scb = (l & 15) << 4;     // staging byte col within 256B row

    const char* rmB = (const char*)(rmb + ((size_t)b * NN + i0) * NN + kb0);
    const char* eTB = (const char*)(eT_src + (size_t)b * DD * NN + kb0);

    f32x4 acc0 = {}, acc1 = {};

    // wave w stages rows [w*8, w*8+8) of both SB and SA (2 gl_lds each)
    #define STAGE(buf, step) do {                                               \
        const int ksb = (step) * 256;                                           \
        _Pragma("unroll")                                                       \
        for (int g = 0; g < 2; g++) {                                           \
            int r0 = w * 8 + g * 4;                                             \
            int lr = r0 + sr;                                                   \
            int sc = scb ^ ((lr & 7) << 4);                                     \
            gl_lds16(rmB + (size_t)lr * (NN*2) + ksb + sc,                      \
                     (char*)&SB[buf][0] + r0 * 256);                            \
            gl_lds16(eTB + (size_t)lr * (NN*2) + ksb + sc,                      \
                     (char*)&SA[buf][0] + r0 * 256);                            \
        }                                                                       \
    } while (0)

    const int rowB  = it * 16 + lo;         // rm row (i)
    const int rowA0 = dh * 32 + lo;         // eT row, dt=0
    const int rowA1 = dh * 32 + 16 + lo;    // eT row, dt=1
    const int xr = (lo & 7) << 4;           // all three rows ≡ lo (mod 8)

    #define COMPUTE(buf) do {                                                   \
        const char* Ab = (const char*)&SA[buf][0];                              \
        const char* Bb = (const char*)&SB[buf][0];                              \
        _Pragma("unroll")                                                       \
        for (int kk = 0; kk < 4; kk++) {                                        \
            int co = ((kk << 6) | (hi << 4)) ^ xr;                              \
            u32x4 fB  = *(const u32x4*)(Bb + rowB  * 256 + co);                 \
            u32x4 fA0 = *(const u32x4*)(Ab + rowA0 * 256 + co);                 \
            u32x4 fA1 = *(const u32x4*)(Ab + rowA1 * 256 + co);                 \
            acc0 = __builtin_amdgcn_mfma_f32_16x16x32_bf16(                     \
                __builtin_bit_cast(bf16x8, fA0), __builtin_bit_cast(bf16x8, fB), acc0, 0, 0, 0); \
            acc1 = __builtin_amdgcn_mfma_f32_16x16x32_bf16(                     \
                __builtin_bit_cast(bf16x8, fA1), __builtin_bit_cast(bf16x8, fB), acc1, 0, 0, 0); \
        }                                                                       \
    } while (0)

    STAGE(0, 0);
    __syncthreads();
    #pragma unroll
    for (int step = 0; step < 8; step++) {
        const int cur = step & 1;
        if (step < 7) STAGE(cur ^ 1, step + 1);
        COMPUTE(cur);
        __syncthreads();
    }
    #undef STAGE
    #undef COMPUTE

    // partial[ks][b][i][d]: i = i0+it*16+lo (col), d = dh*32 + dt*16 + hi*4 + r (row)
    float* pp = partial + (((size_t)ks * BB + b) * NN + i0 + it * 16 + lo) * DD
              + dh * 32 + hi * 4;
    *(f32x4*)pp = acc0;
    *(f32x4*)(pp + 16) = acc1;
}

// ---------------- reduce K-halves + shift + l2norm epilogue (+ transposed eT)
__global__ __launch_bounds__(256) void reduce_epi(
        const float* __restrict__ partial,
        const float* __restrict__ e_src,
        const float* __restrict__ rowsum_g,
        const int* __restrict__ echo,
        float* __restrict__ e_dst,
        unsigned short* __restrict__ eT_dst,
        int layer) {
    __shared__ unsigned short tile[64][72];
    int t = threadIdx.x;
    int tok0 = blockIdx.x * 64;
    int lt = t >> 2;
    int tt = tok0 + lt;
    int dd = (t & 3) * 16;

    const float* p0 = partial + (size_t)tt * DD + dd;
    const float* p1 = partial + ((size_t)BB * NN + tt) * DD + dd;
    const float* es = e_src + (size_t)tt * DD + dd;
    float rs = rowsum_g[tt];
    float coef = (layer < echo[tt]) ? DELTA : 0.f;

    f32x4 u[4];
    float ss = 0.f;
    #pragma unroll
    for (int q = 0; q < 4; q++) {
        f32x4 a = *(const f32x4*)(p0 + q * 4) + *(const f32x4*)(p1 + q * 4);
        f32x4 e = *(const f32x4*)(es + q * 4);
        f32x4 uu = e + coef * (e * rs - a);
        u[q] = uu;
        ss += uu.x*uu.x + uu.y*uu.y + uu.z*uu.z + uu.w*uu.w;
    }
    ss += __shfl_xor(ss, 1);
    ss += __shfl_xor(ss, 2);
    float scale = 1.f / fmaxf(sqrtf(ss), 1e-12f);
    float* dst = e_dst + (size_t)tt * DD + dd;
    #pragma unroll
    for (int q = 0; q < 4; q++) {
        f32x4 o = u[q] * scale;
        *(f32x4*)(dst + q * 4) = o;
        tile[lt][dd + q*4 + 0] = f2b(o.x);
        tile[lt][dd + q*4 + 1] = f2b(o.y);
        tile[lt][dd + q*4 + 2] = f2b(o.z);
        tile[lt][dd + q*4 + 3] = f2b(o.w);
    }
    __syncthreads();
    int b  = tok0 / NN;
    int tb = tok0 % NN;
    for (int idx = t; idx < 64 * 64; idx += 256) {
        int d = idx >> 6, j = idx & 63;
        eT_dst[((size_t)b * DD + d) * NN + tb + j] = tile[j][d];
    }
}

// ---------------- R6 single-kernel layer (fallback when partial buffer doesn't fit)
__global__ __launch_bounds__(256, 2) void layer_mfma(
        const unsigned short* __restrict__ rmb,
        const unsigned short* __restrict__ eT_src,
        const float* __restrict__ e_src,
        const float* __restrict__ rowsum_g,
        const int* __restrict__ echo,
        float* __restrict__ e_dst,
        unsigned short* __restrict__ eT_dst,
        int layer) {
    __shared__ u32x4 SA[2][64 * 16];
    __shared__ u32x4 SB[2][32 * 16];
    __shared__ float redSS[2][2][16];

    const int t = threadIdx.x;
    const int w = t >> 6, l = t & 63;
    const int lo = l & 15, hi = l >> 4;
    const int wi = w >> 1, dh = w & 1;
    const int b = blockIdx.y;
    const int i0 = blockIdx.x * 32;

    const int sr  = l >> 4;
    const int scb = (l & 15) << 4;

    const char* rm_bytes = (const char*)(rmb + ((size_t)b * NN + i0) * NN);
    const char* eT_bytes = (const char*)(eT_src + (size_t)b * DD * NN);

    f32x4 acc0 = {}, acc1 = {};

    #define STAGE(buf, step) do {                                              \
        const int ksb = (step) * 256;                                          \
        {   int r0 = w * 8;                                                    \
            int lr = r0 + sr;                                                  \
            gl_lds16(rm_bytes + (size_t)lr * (NN*2) + ksb + (scb ^ ((lr&7)<<4)),\
                     (char*)&SB[buf][0] + r0 * 256);                           \
            r0 += 4; lr = r0 + sr;                                             \
            gl_lds16(rm_bytes + (size_t)lr * (NN*2) + ksb + (scb ^ ((lr&7)<<4)),\
                     (char*)&SB[buf][0] + r0 * 256); }                         \
        _Pragma("unroll")                                                      \
        for (int q = 0; q < 4; q++) {                                          \
            int r0 = w * 16 + q * 4;                                           \
            int lr = r0 + sr;                                                  \
            gl_lds16(eT_bytes + (size_t)lr * (NN*2) + ksb + (scb ^ ((lr&7)<<4)),\
                     (char*)&SA[buf][0] + r0 * 256); }                         \
    } while (0)

    const int rowB = wi * 16 + lo;
    const int rowA0 = dh * 32 + lo;
    const int rowA1 = dh * 32 + 16 + lo;
    const int xr = (lo & 7) << 4;

    #define COMPUTE(buf) do {                                                  \
        const char* Ab = (const char*)&SA[buf][0];                             \
        const char* Bb = (const char*)&SB[buf][0];                             \
        _Pragma("unroll")                                                      \
        for (int kk = 0; kk < 4; kk++) {                                       \
            int co = ((kk << 6) | (hi << 4)) ^ xr;                             \
            u32x4 fB  = *(const u32x4*)(Bb + rowB  * 256 + co);                \
            u32x4 fA0 = *(const u32x4*)(Ab + rowA0 * 256 + co);                \
            u32x4 fA1 = *(const u32x4*)(Ab + rowA1 * 256 + co);                \
            acc0 = __builtin_amdgcn_mfma_f32_16x16x32_bf16(                    \
                __builtin_bit_cast(bf16x8, fA0), __builtin_bit_cast(bf16x8, fB), acc0, 0, 0, 0); \
            acc1 = __builtin_amdgcn_mfma_f32_16x16x32_bf16(                    \
                __builtin_bit_cast(bf16x8, fA1), __builtin_bit_cast(bf16x8, fB), acc1, 0, 0, 0); \
        }                                                                      \
    } while (0)

    STAGE(0, 0);
    __syncthreads();
    #pragma unroll
    for (int step = 0; step < 16; step++) {
        const int cur = step & 1;
        if (step < 15) STAGE(cur ^ 1, step + 1);
        COMPUTE(cur);
        __syncthreads();
    }
    #undef STAGE
    #undef COMPUTE

    const size_t gi = (size_t)b * NN + i0 + wi * 16 + lo;
    const float rs = rowsum_g[gi];
    const float coef = (layer < echo[gi]) ? DELTA : 0.f;
    const size_t eb = gi * DD + dh * 32 + hi * 4;
    f32x4 e0 = *(const f32x4*)(e_src + eb);
    f32x4 e1 = *(const f32x4*)(e_src + eb + 16);
    f32x4 u0 = e0 + coef * (e0 * rs - acc0);
    f32x4 u1 = e1 + coef * (e1 * rs - acc1);
    float ss = u0.x*u0.x + u0.y*u0.y + u0.z*u0.z + u0.w*u0.w
             + u1.x*u1.x + u1.y*u1.y + u1.z*u1.z + u1.w*u1.w;
    ss += __shfl_xor(ss, 16);
    ss += __shfl_xor(ss, 32);
    if (hi == 0) redSS[wi][dh][lo] = ss;
    __syncthreads();
    float sst = redSS[wi][0][lo] + redSS[wi][1][lo];
    float scale = 1.f / fmaxf(sqrtf(sst), 1e-12f);
    u0 *= scale;
    u1 *= scale;
    *(f32x4*)(e_dst + eb) = u0;
    *(f32x4*)(e_dst + eb + 16) = u1;
    unsigned short* ep = eT_dst + (size_t)b * DD * NN;
    const int i = i0 + wi * 16 + lo;
    const int d0 = dh * 32 + hi * 4;
    ep[(size_t)(d0 + 0)  * NN + i] = f2b(u0.x);
    ep[(size_t)(d0 + 1)  * NN + i] = f2b(u0.y);
    ep[(size_t)(d0 + 2)  * NN + i] = f2b(u0.z);
    ep[(size_t)(d0 + 3)  * NN + i] = f2b(u0.w);
    ep[(size_t)(d0 + 16) * NN + i] = f2b(u1.x);
    ep[(size_t)(d0 + 17) * NN + i] = f2b(u1.y);
    ep[(size_t)(d0 + 18) * NN + i] = f2b(u1.z);
    ep[(size_t)(d0 + 19) * NN + i] = f2b(u1.w);
}

// ---------------- deep fallback (no bf16 cache fits): direct fp32 reads
__global__ __launch_bounds__(512, 4) void layer_step_fb(
        const float* __restrict__ rm_,
        const unsigned short* __restrict__ eT_src,
        const float* __restrict__ e_src,
        const float* __restrict__ rowsum_g,
        const int* __restrict__ echo,
        float* __restrict__ e_dst,
        unsigned short* __restrict__ eT_dst,
        int layer) {
    __shared__ float redAcc[3][2][64][20];

    int t = threadIdx.x;
    int w = t >> 6, l = t & 63;
    int b = blockIdx.y;
    int i0 = blockIdx.x * 32;
    int wi = w & 1;
    int kq = w >> 1;
    int lane_lo = l & 15, lane_hi = l >> 4;
    int i = i0 + wi * 16 + lane_lo;
    size_t gi = (size_t)b * NN + i;
    int kbase = kq * (NN / 4) + 8 * lane_hi;

    int echo_pre = echo[gi];
    float rs = rowsum_g[gi];

    const unsigned short* eT_b = eT_src + (size_t)b * DD * NN;
    const unsigned short* ea0 = eT_b + (size_t)(lane_lo)      * NN + kbase;
    const unsigned short* ea1 = eT_b + (size_t)(16 + lane_lo) * NN + kbase;
    const unsigned short* ea2 = eT_b + (size_t)(32 + lane_lo) * NN + kbase;
    const unsigned short* ea3 = eT_b + (size_t)(48 + lane_lo) * NN + kbase;

    f32x4 acc[4] = {};
    const float* rmp32 = rm_ + gi * NN + kbase;

    #pragma unroll
    for (int j = 0; j < 16; j++) {
        const int o = 32 * j;
        f32x4 lo4 = *(const f32x4*)(rmp32 + o);
        f32x4 hi4 = *(const f32x4*)(rmp32 + o + 4);
        u32x4 ob;
        ob.x = (unsigned)f2b(lo4.x) | ((unsigned)f2b(lo4.y) << 16);
        ob.y = (unsigned)f2b(lo4.z) | ((unsigned)f2b(lo4.w) << 16);
        ob.z = (unsigned)f2b(hi4.x) | ((unsigned)f2b(hi4.y) << 16);
        ob.w = (unsigned)f2b(hi4.z) | ((unsigned)f2b(hi4.w) << 16);
        bf16x8 bfrag = __builtin_bit_cast(bf16x8, ob);
        acc[0] = __builtin_amdgcn_mfma_f32_16x16x32_bf16(
            __builtin_bit_cast(bf16x8, *(const u32x4*)(ea0 + o)), bfrag, acc[0], 0, 0, 0);
        acc[1] = __builtin_amdgcn_mfma_f32_16x16x32_bf16(
            __builtin_bit_cast(bf16x8, *(const u32x4*)(ea1 + o)), bfrag, acc[1], 0, 0, 0);
        acc[2] = __builtin_amdgcn_mfma_f32_16x16x32_bf16(
            __builtin_bit_cast(bf16x8, *(const u32x4*)(ea2 + o)), bfrag, acc[2], 0, 0, 0);
        acc[3] = __builtin_amdgcn_mfma_f32_16x16x32_bf16(
            __builtin_bit_cast(bf16x8, *(const u32x4*)(ea3 + o)), bfrag, acc[3], 0, 0, 0);
    }

    if (kq > 0) {
        #pragma unroll
        for (int f = 0; f < 4; f++)
            *(f32x4*)(&redAcc[kq - 1][wi][l][4 * f]) = acc[f];
    }
    __syncthreads();
    if (kq == 0) {
        #pragma unroll
        for (int f = 0; f < 4; f++) {
            acc[f] += *(const f32x4*)(&redAcc[0][wi][l][4 * f]);
            acc[f] += *(const f32x4*)(&redAcc[1][wi][l][4 * f]);
            acc[f] += *(const f32x4*)(&redAcc[2][wi][l][4 * f]);
        }
        float coef = DELTA * ((layer < echo_pre) ? 1.f : 0.f);
        size_t ebase = gi * DD;
        f32x4 upd[4];
        float ss = 0.f;
        #pragma unroll
        for (int f = 0; f < 4; f++) {
            f32x4 e = *(const f32x4*)(e_src + ebase + 16 * f + 4 * lane_hi);
            f32x4 u = e + coef * (e * rs - acc[f]);
            upd[f] = u;
            ss += u.x*u.x + u.y*u.y + u.z*u.z + u.w*u.w;
        }
        ss += __shfl_xor(ss, 16);
        ss += __shfl_xor(ss, 32);
        float scale = 1.f / fmaxf(sqrtf(ss), 1e-12f);
        unsigned short* ep = eT_dst + (size_t)b * DD * NN;
        #pragma unroll
        for (int f = 0; f < 4; f++) {
            f32x4 o = upd[f] * scale;
            *(f32x4*)(e_dst + ebase + 16 * f + 4 * lane_hi) = o;
            int dbase = 16 * f + 4 * lane_hi;
            ep[(size_t)(dbase + 0) * NN + i] = f2b(o.x);
            ep[(size_t)(dbase + 1) * NN + i] = f2b(o.y);
            ep[(size_t)(dbase + 2) * NN + i] = f2b(o.z);
            ep[(size_t)(dbase + 3) * NN + i] = f2b(o.w);
        }
    }
}

extern "C" void kernel_launch(void* const* d_in, const int* in_sizes, int n_in,
                              void* d_out, int out_size, void* d_ws, size_t ws_size,
                              hipStream_t stream) {
    const float* emb  = (const float*)d_in[0];
    const float* freq = (const float*)d_in[1];
    const float* rm   = (const float*)d_in[2];
    float* out = (float*)d_out;
    char* ws = (char*)d_ws;

    const size_t eBytes   = (size_t)BB * NN * DD * 4;   // 4 MB
    const size_t eTBytes  = (size_t)BB * DD * NN * 2;   // 2 MB
    const size_t bnBytes  = (size_t)BB * NN * 4;        // 64 KB
    const size_t rmbBytes = (size_t)BB * NN * NN * 2;   // 67 MB
    const size_t pBytes   = (size_t)2 * BB * NN * DD * 4; // 8 MB
    float* e_f32[2] = { (float*)ws, (float*)(ws + eBytes) };
    unsigned short* eT[2] = { (unsigned short*)(ws + 2*eBytes),
                              (unsigned short*)(ws + 2*eBytes + eTBytes) };
    float* rowsum = (float*)(ws + 2*eBytes + 2*eTBytes);
    int* echo = (int*)(ws + 2*eBytes + 2*eTBytes + bnBytes);
    unsigned short* rmb = (unsigned short*)(ws + 2*eBytes + 2*eTBytes + 2*bnBytes);
    size_t need_cached = 2*eBytes + 2*eTBytes + 2*bnBytes + rmbBytes;
    float* part = (float*)(ws + need_cached);
    size_t need_split = need_cached + pBytes;

    int mode = (ws_size >= need_split) ? 2 : (ws_size >= need_cached) ? 1 : 0;

    prep_norm<<<dim3(BB*NN/64), dim3(256), 0, stream>>>(emb, freq, e_f32[0], eT[0], echo);

    if (mode == 2) {
        cast_rowsum<true><<<dim3(BB*NN/4), dim3(256), 0, stream>>>(rm, rmb, rowsum);
        for (int l = 0; l < 5; l++) {
            float* dst = (l == 4) ? out : e_f32[(l + 1) & 1];
            layer_ksplit<<<dim3(NN/64, 2, BB), dim3(512), 0, stream>>>(
                rmb, eT[l & 1], part);
            reduce_epi<<<dim3(BB*NN/64), dim3(256), 0, stream>>>(
                part, e_f32[l & 1], rowsum, echo, dst, eT[(l + 1) & 1], l);
        }
    } else if (mode == 1) {
        cast_rowsum<true><<<dim3(BB*NN/4), dim3(256), 0, stream>>>(rm, rmb, rowsum);
        for (int l = 0; l < 5; l++) {
            float* dst = (l == 4) ? out : e_f32[(l + 1) & 1];
            layer_mfma<<<dim3(NN/32, BB), dim3(256), 0, stream>>>(
                rmb, eT[l & 1], e_f32[l & 1], rowsum, echo,
                dst, eT[(l + 1) & 1], l);
        }
    } else {
        cast_rowsum<false><<<dim3(BB*NN/4), dim3(256), 0, stream>>>(rm, nullptr, rowsum);
        for (int l = 0; l < 5; l++) {
            float* dst = (l == 4) ? out : e_f32[(l + 1) & 1];
            layer_step_fb<<<dim3(NN/32, BB), dim3(512), 0, stream>>>(
                rm, eT[l & 1], e_f32[l & 1], rowsum, echo,
                dst, eT[(l + 1) & 1], l);
        }
    }
}

// Round 9
// 141.662 us; speedup vs baseline: 1.6393x; 1.0101x over previous
//
#include <hip/hip_runtime.h>
#include <stdint.h>

#define BB 8
#define NN 2048
#define DD 64
#define DELTA 0.1625f
#define FREQ_SCALE 0.325f

typedef __bf16 bf16x8 __attribute__((ext_vector_type(8)));
typedef float f32x4 __attribute__((ext_vector_type(4)));
typedef unsigned int u32x4 __attribute__((ext_vector_type(4)));
typedef unsigned int u32x2 __attribute__((ext_vector_type(2)));

static __device__ __forceinline__ unsigned short f2b(float x) {
    union { float f; unsigned int u; } c; c.f = x;
    unsigned int r = (c.u + 0x7FFFu + ((c.u >> 16) & 1u)) >> 16;
    return (unsigned short)r;
}

static __device__ __forceinline__ void gl_lds16(const void* g, void* l) {
    __builtin_amdgcn_global_load_lds(
        (const __attribute__((address_space(1))) void*)g,
        (__attribute__((address_space(3))) void*)l, 16, 0, 0);
}

// ---------------- prep: normalize embeddings, echo layers, e0 (f32) + e0^T (bf16)
__global__ __launch_bounds__(256) void prep_norm(
        const float* __restrict__ emb, const float* __restrict__ freq,
        float* __restrict__ e0, unsigned short* __restrict__ eT0,
        int* __restrict__ echo) {
    __shared__ unsigned short tile[64][72];
    int t = threadIdx.x;
    int tok0 = blockIdx.x * 64;
    int lt = t >> 2;
    int tt = tok0 + lt;
    int dd = (t & 3) * 16;

    const float* src = emb + (size_t)tt * DD + dd;
    f32x4 v[4];
    float ss = 0.f;
    #pragma unroll
    for (int q = 0; q < 4; q++) {
        v[q] = *(const f32x4*)(src + q * 4);
        ss += v[q].x*v[q].x + v[q].y*v[q].y + v[q].z*v[q].z + v[q].w*v[q].w;
    }
    ss += __shfl_xor(ss, 1);
    ss += __shfl_xor(ss, 2);
    float scale = 1.f / fmaxf(sqrtf(ss), 1e-12f);
    float* dst = e0 + (size_t)tt * DD + dd;
    #pragma unroll
    for (int q = 0; q < 4; q++) {
        f32x4 o = v[q] * scale;
        *(f32x4*)(dst + q * 4) = o;
        tile[lt][dd + q*4 + 0] = f2b(o.x);
        tile[lt][dd + q*4 + 1] = f2b(o.y);
        tile[lt][dd + q*4 + 2] = f2b(o.z);
        tile[lt][dd + q*4 + 3] = f2b(o.w);
    }
    if ((t & 3) == 0) {
        int el = 1 + (int)floorf(freq[tt] * FREQ_SCALE);
        el = el < 1 ? 1 : (el > 5 ? 5 : el);
        echo[tt] = el;
    }
    __syncthreads();
    int b  = tok0 / NN;
    int tb = tok0 % NN;
    for (int idx = t; idx < 64 * 64; idx += 256) {
        int d = idx >> 6, j = idx & 63;
        eT0[((size_t)b * DD + d) * NN + tb + j] = tile[j][d];
    }
}

// ---------------- cast + rowsum: one wave per rm row, pure streaming
template<bool WRB>
__global__ __launch_bounds__(256) void cast_rowsum(
        const float* __restrict__ rm, unsigned short* __restrict__ rmb,
        float* __restrict__ rowsum) {
    int gw = (int)((blockIdx.x * 256 + threadIdx.x) >> 6);   // row 0..B*N-1
    int l = threadIdx.x & 63;
    const float* src = rm + (size_t)gw * NN;
    f32x4 v[8];
    #pragma unroll
    for (int q = 0; q < 8; q++)
        v[q] = *(const f32x4*)(src + q * 256 + l * 4);
    float s = 0.f;
    #pragma unroll
    for (int q = 0; q < 8; q++)
        s += (v[q].x + v[q].y) + (v[q].z + v[q].w);
    if constexpr (WRB) {
        unsigned short* dst = rmb + (size_t)gw * NN;
        #pragma unroll
        for (int q = 0; q < 8; q++) {
            u32x2 o;
            o.x = (unsigned)f2b(v[q].x) | ((unsigned)f2b(v[q].y) << 16);
            o.y = (unsigned)f2b(v[q].z) | ((unsigned)f2b(v[q].w) << 16);
            *(u32x2*)(dst + q * 256 + l * 4) = o;
        }
    }
    #pragma unroll
    for (int m = 1; m < 64; m <<= 1) s += __shfl_xor(s, m);
    if (l == 0) rowsum[gw] = s;
}

// ---------------- layer K-split kernel, counted-vmcnt 3-buffer pipeline (T3/T4)
// grid (NN/64, 2, BB), block 512 = 8 waves: it = w&3 (16-row i-tile), dh = w>>2.
// BK=64: tiles rm[64 rows][128B], eT[64 rows][128B]; 3 buffers; 16 K-steps.
// Protocol: vmcnt(2) (never 0 mid-loop) + raw s_barrier; ISSUE(s+2) after barrier.
__global__ __launch_bounds__(512, 2) void layer_ksplit(
        const unsigned short* __restrict__ rmb,     // [B][N][N] bf16
        const unsigned short* __restrict__ eT_src,  // [B][64][N] bf16
        float* __restrict__ partial) {              // [2][B][N][64] f32
    __shared__ char SA3[3][8192];   // eT tiles
    __shared__ char SB3[3][8192];   // rm tiles

    const int t = threadIdx.x;
    const int w = t >> 6, l = t & 63;
    const int lo = l & 15, hi = l >> 4;
    const int it = w & 3, dh = w >> 2;
    const int i0 = blockIdx.x * 64;
    const int ks = blockIdx.y;
    const int b  = blockIdx.z;
    const int kb0 = ks * (NN / 2);

    const char* rmB = (const char*)(rmb + ((size_t)b * NN + i0) * NN + kb0);
    const char* eTB = (const char*)(eT_src + (size_t)b * DD * NN + kb0);

    // staging: wave w stages rows [8w,8w+8); lane l: row 8w+(l>>3), slot l&7.
    // LDS dest = uniform base (w*1024) + lane*16  -> linear row-major [64][128B].
    // source col pre-swizzled so LDS slot p holds global slot p^(row&7).
    const size_t srow = (size_t)(w * 8 + (l >> 3)) * (NN * 2);
    const int csrc = ((l & 7) ^ (l >> 3)) << 4;

    f32x4 acc0 = {}, acc1 = {};

    const int rowB  = it * 16 + lo;         // rm row (i)
    const int rowA0 = dh * 32 + lo;         // eT row, dt=0
    const int rowA1 = dh * 32 + 16 + lo;    // eT row, dt=1
    const int xr = (lo & 7) << 4;           // read-side XOR key (rows ≡ lo mod 8)

#define ISSUE(bi, step) do {                                       \
    const int ksb = (step) * 128;                                  \
    gl_lds16(rmB + srow + ksb + csrc, &SB3[bi][w * 1024]);         \
    gl_lds16(eTB + srow + ksb + csrc, &SA3[bi][w * 1024]);         \
} while (0)

#define COMP(bi) do {                                              \
    _Pragma("unroll")                                              \
    for (int kk = 0; kk < 2; kk++) {                               \
        int co = ((kk << 6) | (hi << 4)) ^ xr;                     \
        u32x4 fB  = *(const u32x4*)(&SB3[bi][rowB  * 128 + co]);   \
        u32x4 fA0 = *(const u32x4*)(&SA3[bi][rowA0 * 128 + co]);   \
        u32x4 fA1 = *(const u32x4*)(&SA3[bi][rowA1 * 128 + co]);   \
        acc0 = __builtin_amdgcn_mfma_f32_16x16x32_bf16(            \
            __builtin_bit_cast(bf16x8, fA0), __builtin_bit_cast(bf16x8, fB), acc0, 0, 0, 0); \
        acc1 = __builtin_amdgcn_mfma_f32_16x16x32_bf16(            \
            __builtin_bit_cast(bf16x8, fA1), __builtin_bit_cast(bf16x8, fB), acc1, 0, 0, 0); \
    }                                                              \
} while (0)

    ISSUE(0, 0);
    ISSUE(1, 1);
    #pragma unroll
    for (int s = 0; s < 16; s++) {
        if (s < 15) asm volatile("s_waitcnt vmcnt(2)" ::: "memory");
        else        asm volatile("s_waitcnt vmcnt(0)" ::: "memory");
        __builtin_amdgcn_s_barrier();
        __builtin_amdgcn_sched_barrier(0);
        if (s < 14) {
            const int nb = (s + 2) % 3;
            if (nb == 0)      ISSUE(0, s + 2);
            else if (nb == 1) ISSUE(1, s + 2);
            else              ISSUE(2, s + 2);
        }
        const int cb = s % 3;
        if (cb == 0)      COMP(0);
        else if (cb == 1) COMP(1);
        else              COMP(2);
    }
#undef ISSUE
#undef COMP

    // partial[ks][b][i][d]: i = i0+it*16+lo, d = dh*32 + dt*16 + hi*4 + r
    float* pp = partial + (((size_t)ks * BB + b) * NN + i0 + it * 16 + lo) * DD
              + dh * 32 + hi * 4;
    *(f32x4*)pp = acc0;
    *(f32x4*)(pp + 16) = acc1;
}

// ---------------- reduce K-halves + shift + l2norm epilogue (+ transposed eT)
__global__ __launch_bounds__(256) void reduce_epi(
        const float* __restrict__ partial,
        const float* __restrict__ e_src,
        const float* __restrict__ rowsum_g,
        const int* __restrict__ echo,
        float* __restrict__ e_dst,
        unsigned short* __restrict__ eT_dst,
        int layer) {
    __shared__ unsigned short tile[64][72];
    int t = threadIdx.x;
    int tok0 = blockIdx.x * 64;
    int lt = t >> 2;
    int tt = tok0 + lt;
    int dd = (t & 3) * 16;

    const float* p0 = partial + (size_t)tt * DD + dd;
    const float* p1 = partial + ((size_t)BB * NN + tt) * DD + dd;
    const float* es = e_src + (size_t)tt * DD + dd;
    float rs = rowsum_g[tt];
    float coef = (layer < echo[tt]) ? DELTA : 0.f;

    f32x4 u[4];
    float ss = 0.f;
    #pragma unroll
    for (int q = 0; q < 4; q++) {
        f32x4 a = *(const f32x4*)(p0 + q * 4) + *(const f32x4*)(p1 + q * 4);
        f32x4 e = *(const f32x4*)(es + q * 4);
        f32x4 uu = e + coef * (e * rs - a);
        u[q] = uu;
        ss += uu.x*uu.x + uu.y*uu.y + uu.z*uu.z + uu.w*uu.w;
    }
    ss += __shfl_xor(ss, 1);
    ss += __shfl_xor(ss, 2);
    float scale = 1.f / fmaxf(sqrtf(ss), 1e-12f);
    float* dst = e_dst + (size_t)tt * DD + dd;
    #pragma unroll
    for (int q = 0; q < 4; q++) {
        f32x4 o = u[q] * scale;
        *(f32x4*)(dst + q * 4) = o;
        tile[lt][dd + q*4 + 0] = f2b(o.x);
        tile[lt][dd + q*4 + 1] = f2b(o.y);
        tile[lt][dd + q*4 + 2] = f2b(o.z);
        tile[lt][dd + q*4 + 3] = f2b(o.w);
    }
    __syncthreads();
    int b  = tok0 / NN;
    int tb = tok0 % NN;
    for (int idx = t; idx < 64 * 64; idx += 256) {
        int d = idx >> 6, j = idx & 63;
        eT_dst[((size_t)b * DD + d) * NN + tb + j] = tile[j][d];
    }
}

// ---------------- R6 single-kernel layer (fallback when partial buffer doesn't fit)
__global__ __launch_bounds__(256, 2) void layer_mfma(
        const unsigned short* __restrict__ rmb,
        const unsigned short* __restrict__ eT_src,
        const float* __restrict__ e_src,
        const float* __restrict__ rowsum_g,
        const int* __restrict__ echo,
        float* __restrict__ e_dst,
        unsigned short* __restrict__ eT_dst,
        int layer) {
    __shared__ u32x4 SA[2][64 * 16];
    __shared__ u32x4 SB[2][32 * 16];
    __shared__ float redSS[2][2][16];

    const int t = threadIdx.x;
    const int w = t >> 6, l = t & 63;
    const int lo = l & 15, hi = l >> 4;
    const int wi = w >> 1, dh = w & 1;
    const int b = blockIdx.y;
    const int i0 = blockIdx.x * 32;

    const int sr  = l >> 4;
    const int scb = (l & 15) << 4;

    const char* rm_bytes = (const char*)(rmb + ((size_t)b * NN + i0) * NN);
    const char* eT_bytes = (const char*)(eT_src + (size_t)b * DD * NN);

    f32x4 acc0 = {}, acc1 = {};

    #define STAGE(buf, step) do {                                              \
        const int ksb = (step) * 256;                                          \
        {   int r0 = w * 8;                                                    \
            int lr = r0 + sr;                                                  \
            gl_lds16(rm_bytes + (size_t)lr * (NN*2) + ksb + (scb ^ ((lr&7)<<4)),\
                     (char*)&SB[buf][0] + r0 * 256);                           \
            r0 += 4; lr = r0 + sr;                                             \
            gl_lds16(rm_bytes + (size_t)lr * (NN*2) + ksb + (scb ^ ((lr&7)<<4)),\
                     (char*)&SB[buf][0] + r0 * 256); }                         \
        _Pragma("unroll")                                                      \
        for (int q = 0; q < 4; q++) {                                          \
            int r0 = w * 16 + q * 4;                                           \
            int lr = r0 + sr;                                                  \
            gl_lds16(eT_bytes + (size_t)lr * (NN*2) + ksb + (scb ^ ((lr&7)<<4)),\
                     (char*)&SA[buf][0] + r0 * 256); }                         \
    } while (0)

    const int rowB = wi * 16 + lo;
    const int rowA0 = dh * 32 + lo;
    const int rowA1 = dh * 32 + 16 + lo;
    const int xr = (lo & 7) << 4;

    #define COMPUTE(buf) do {                                                  \
        const char* Ab = (const char*)&SA[buf][0];                             \
        const char* Bb = (const char*)&SB[buf][0];                             \
        _Pragma("unroll")                                                      \
        for (int kk = 0; kk < 4; kk++) {                                       \
            int co = ((kk << 6) | (hi << 4)) ^ xr;                             \
            u32x4 fB  = *(const u32x4*)(Bb + rowB  * 256 + co);                \
            u32x4 fA0 = *(const u32x4*)(Ab + rowA0 * 256 + co);                \
            u32x4 fA1 = *(const u32x4*)(Ab + rowA1 * 256 + co);                \
            acc0 = __builtin_amdgcn_mfma_f32_16x16x32_bf16(                    \
                __builtin_bit_cast(bf16x8, fA0), __builtin_bit_cast(bf16x8, fB), acc0, 0, 0, 0); \
            acc1 = __builtin_amdgcn_mfma_f32_16x16x32_bf16(                    \
                __builtin_bit_cast(bf16x8, fA1), __builtin_bit_cast(bf16x8, fB), acc1, 0, 0, 0); \
        }                                                                      \
    } while (0)

    STAGE(0, 0);
    __syncthreads();
    #pragma unroll
    for (int step = 0; step < 16; step++) {
        const int cur = step & 1;
        if (step < 15) STAGE(cur ^ 1, step + 1);
        COMPUTE(cur);
        __syncthreads();
    }
    #undef STAGE
    #undef COMPUTE

    const size_t gi = (size_t)b * NN + i0 + wi * 16 + lo;
    const float rs = rowsum_g[gi];
    const float coef = (layer < echo[gi]) ? DELTA : 0.f;
    const size_t eb = gi * DD + dh * 32 + hi * 4;
    f32x4 e0 = *(const f32x4*)(e_src + eb);
    f32x4 e1 = *(const f32x4*)(e_src + eb + 16);
    f32x4 u0 = e0 + coef * (e0 * rs - acc0);
    f32x4 u1 = e1 + coef * (e1 * rs - acc1);
    float ss = u0.x*u0.x + u0.y*u0.y + u0.z*u0.z + u0.w*u0.w
             + u1.x*u1.x + u1.y*u1.y + u1.z*u1.z + u1.w*u1.w;
    ss += __shfl_xor(ss, 16);
    ss += __shfl_xor(ss, 32);
    if (hi == 0) redSS[wi][dh][lo] = ss;
    __syncthreads();
    float sst = redSS[wi][0][lo] + redSS[wi][1][lo];
    float scale = 1.f / fmaxf(sqrtf(sst), 1e-12f);
    u0 *= scale;
    u1 *= scale;
    *(f32x4*)(e_dst + eb) = u0;
    *(f32x4*)(e_dst + eb + 16) = u1;
    unsigned short* ep = eT_dst + (size_t)b * DD * NN;
    const int i = i0 + wi * 16 + lo;
    const int d0 = dh * 32 + hi * 4;
    ep[(size_t)(d0 + 0)  * NN + i] = f2b(u0.x);
    ep[(size_t)(d0 + 1)  * NN + i] = f2b(u0.y);
    ep[(size_t)(d0 + 2)  * NN + i] = f2b(u0.z);
    ep[(size_t)(d0 + 3)  * NN + i] = f2b(u0.w);
    ep[(size_t)(d0 + 16) * NN + i] = f2b(u1.x);
    ep[(size_t)(d0 + 17) * NN + i] = f2b(u1.y);
    ep[(size_t)(d0 + 18) * NN + i] = f2b(u1.z);
    ep[(size_t)(d0 + 19) * NN + i] = f2b(u1.w);
}

// ---------------- deep fallback (no bf16 cache fits): direct fp32 reads
__global__ __launch_bounds__(512, 4) void layer_step_fb(
        const float* __restrict__ rm_,
        const unsigned short* __restrict__ eT_src,
        const float* __restrict__ e_src,
        const float* __restrict__ rowsum_g,
        const int* __restrict__ echo,
        float* __restrict__ e_dst,
        unsigned short* __restrict__ eT_dst,
        int layer) {
    __shared__ float redAcc[3][2][64][20];

    int t = threadIdx.x;
    int w = t >> 6, l = t & 63;
    int b = blockIdx.y;
    int i0 = blockIdx.x * 32;
    int wi = w & 1;
    int kq = w >> 1;
    int lane_lo = l & 15, lane_hi = l >> 4;
    int i = i0 + wi * 16 + lane_lo;
    size_t gi = (size_t)b * NN + i;
    int kbase = kq * (NN / 4) + 8 * lane_hi;

    int echo_pre = echo[gi];
    float rs = rowsum_g[gi];

    const unsigned short* eT_b = eT_src + (size_t)b * DD * NN;
    const unsigned short* ea0 = eT_b + (size_t)(lane_lo)      * NN + kbase;
    const unsigned short* ea1 = eT_b + (size_t)(16 + lane_lo) * NN + kbase;
    const unsigned short* ea2 = eT_b + (size_t)(32 + lane_lo) * NN + kbase;
    const unsigned short* ea3 = eT_b + (size_t)(48 + lane_lo) * NN + kbase;

    f32x4 acc[4] = {};
    const float* rmp32 = rm_ + gi * NN + kbase;

    #pragma unroll
    for (int j = 0; j < 16; j++) {
        const int o = 32 * j;
        f32x4 lo4 = *(const f32x4*)(rmp32 + o);
        f32x4 hi4 = *(const f32x4*)(rmp32 + o + 4);
        u32x4 ob;
        ob.x = (unsigned)f2b(lo4.x) | ((unsigned)f2b(lo4.y) << 16);
        ob.y = (unsigned)f2b(lo4.z) | ((unsigned)f2b(lo4.w) << 16);
        ob.z = (unsigned)f2b(hi4.x) | ((unsigned)f2b(hi4.y) << 16);
        ob.w = (unsigned)f2b(hi4.z) | ((unsigned)f2b(hi4.w) << 16);
        bf16x8 bfrag = __builtin_bit_cast(bf16x8, ob);
        acc[0] = __builtin_amdgcn_mfma_f32_16x16x32_bf16(
            __builtin_bit_cast(bf16x8, *(const u32x4*)(ea0 + o)), bfrag, acc[0], 0, 0, 0);
        acc[1] = __builtin_amdgcn_mfma_f32_16x16x32_bf16(
            __builtin_bit_cast(bf16x8, *(const u32x4*)(ea1 + o)), bfrag, acc[1], 0, 0, 0);
        acc[2] = __builtin_amdgcn_mfma_f32_16x16x32_bf16(
            __builtin_bit_cast(bf16x8, *(const u32x4*)(ea2 + o)), bfrag, acc[2], 0, 0, 0);
        acc[3] = __builtin_amdgcn_mfma_f32_16x16x32_bf16(
            __builtin_bit_cast(bf16x8, *(const u32x4*)(ea3 + o)), bfrag, acc[3], 0, 0, 0);
    }

    if (kq > 0) {
        #pragma unroll
        for (int f = 0; f < 4; f++)
            *(f32x4*)(&redAcc[kq - 1][wi][l][4 * f]) = acc[f];
    }
    __syncthreads();
    if (kq == 0) {
        #pragma unroll
        for (int f = 0; f < 4; f++) {
            acc[f] += *(const f32x4*)(&redAcc[0][wi][l][4 * f]);
            acc[f] += *(const f32x4*)(&redAcc[1][wi][l][4 * f]);
            acc[f] += *(const f32x4*)(&redAcc[2][wi][l][4 * f]);
        }
        float coef = DELTA * ((layer < echo_pre) ? 1.f : 0.f);
        size_t ebase = gi * DD;
        f32x4 upd[4];
        float ss = 0.f;
        #pragma unroll
        for (int f = 0; f < 4; f++) {
            f32x4 e = *(const f32x4*)(e_src + ebase + 16 * f + 4 * lane_hi);
            f32x4 u = e + coef * (e * rs - acc[f]);
            upd[f] = u;
            ss += u.x*u.x + u.y*u.y + u.z*u.z + u.w*u.w;
        }
        ss += __shfl_xor(ss, 16);
        ss += __shfl_xor(ss, 32);
        float scale = 1.f / fmaxf(sqrtf(ss), 1e-12f);
        unsigned short* ep = eT_dst + (size_t)b * DD * NN;
        #pragma unroll
        for (int f = 0; f < 4; f++) {
            f32x4 o = upd[f] * scale;
            *(f32x4*)(e_dst + ebase + 16 * f + 4 * lane_hi) = o;
            int dbase = 16 * f + 4 * lane_hi;
            ep[(size_t)(dbase + 0) * NN + i] = f2b(o.x);
            ep[(size_t)(dbase + 1) * NN + i] = f2b(o.y);
            ep[(size_t)(dbase + 2) * NN + i] = f2b(o.z);
            ep[(size_t)(dbase + 3) * NN + i] = f2b(o.w);
        }
    }
}

extern "C" void kernel_launch(void* const* d_in, const int* in_sizes, int n_in,
                              void* d_out, int out_size, void* d_ws, size_t ws_size,
                              hipStream_t stream) {
    const float* emb  = (const float*)d_in[0];
    const float* freq = (const float*)d_in[1];
    const float* rm   = (const float*)d_in[2];
    float* out = (float*)d_out;
    char* ws = (char*)d_ws;

    const size_t eBytes   = (size_t)BB * NN * DD * 4;   // 4 MB
    const size_t eTBytes  = (size_t)BB * DD * NN * 2;   // 2 MB
    const size_t bnBytes  = (size_t)BB * NN * 4;        // 64 KB
    const size_t rmbBytes = (size_t)BB * NN * NN * 2;   // 67 MB
    const size_t pBytes   = (size_t)2 * BB * NN * DD * 4; // 8 MB
    float* e_f32[2] = { (float*)ws, (float*)(ws + eBytes) };
    unsigned short* eT[2] = { (unsigned short*)(ws + 2*eBytes),
                              (unsigned short*)(ws + 2*eBytes + eTBytes) };
    float* rowsum = (float*)(ws + 2*eBytes + 2*eTBytes);
    int* echo = (int*)(ws + 2*eBytes + 2*eTBytes + bnBytes);
    unsigned short* rmb = (unsigned short*)(ws + 2*eBytes + 2*eTBytes + 2*bnBytes);
    size_t need_cached = 2*eBytes + 2*eTBytes + 2*bnBytes + rmbBytes;
    float* part = (float*)(ws + need_cached);
    size_t need_split = need_cached + pBytes;

    int mode = (ws_size >= need_split) ? 2 : (ws_size >= need_cached) ? 1 : 0;

    prep_norm<<<dim3(BB*NN/64), dim3(256), 0, stream>>>(emb, freq, e_f32[0], eT[0], echo);

    if (mode == 2) {
        cast_rowsum<true><<<dim3(BB*NN/4), dim3(256), 0, stream>>>(rm, rmb, rowsum);
        for (int l = 0; l < 5; l++) {
            float* dst = (l == 4) ? out : e_f32[(l + 1) & 1];
            layer_ksplit<<<dim3(NN/64, 2, BB), dim3(512), 0, stream>>>(
                rmb, eT[l & 1], part);
            reduce_epi<<<dim3(BB*NN/64), dim3(256), 0, stream>>>(
                part, e_f32[l & 1], rowsum, echo, dst, eT[(l + 1) & 1], l);
        }
    } else if (mode == 1) {
        cast_rowsum<true><<<dim3(BB*NN/4), dim3(256), 0, stream>>>(rm, rmb, rowsum);
        for (int l = 0; l < 5; l++) {
            float* dst = (l == 4) ? out : e_f32[(l + 1) & 1];
            layer_mfma<<<dim3(NN/32, BB), dim3(256), 0, stream>>>(
                rmb, eT[l & 1], e_f32[l & 1], rowsum, echo,
                dst, eT[(l + 1) & 1], l);
        }
    } else {
        cast_rowsum<false><<<dim3(BB*NN/4), dim3(256), 0, stream>>>(rm, nullptr, rowsum);
        for (int l = 0; l < 5; l++) {
            float* dst = (l == 4) ? out : e_f32[(l + 1) & 1];
            layer_step_fb<<<dim3(NN/32, BB), dim3(512), 0, stream>>>(
                rm, eT[l & 1], e_f32[l & 1], rowsum, echo,
                dst, eT[(l + 1) & 1], l);
        }
    }
}